// Round 12
// baseline (26.998 us; speedup 1.0000x reference)
//
#include <hip/hip_runtime.h>
#include <math.h>

#define NF 40
#define ED 64
#define NP 780      // 40*39/2
#define GPB 4       // batches per block (TWO waves each)
#define BT 512      // 8 waves
#define NTT 49      // 49 tiles x 16 pairs = 784 >= 780

typedef __attribute__((ext_vector_type(8))) _Float16 f16x8;
typedef __attribute__((ext_vector_type(2))) __fp16  fp16x2;
typedef __attribute__((ext_vector_type(4))) float   f32x4;

// xor-k add via VALU permlane swaps (gfx950) -- keeps the LDS pipe free.
__device__ inline float xadd16(float v) {
#if __has_builtin(__builtin_amdgcn_permlane16_swap)
    auto r = __builtin_amdgcn_permlane16_swap(__float_as_uint(v), __float_as_uint(v), false, false);
    return __uint_as_float(r[0]) + __uint_as_float(r[1]);
#else
    return v + __shfl_xor(v, 16);
#endif
}
__device__ inline float xadd32(float v) {
#if __has_builtin(__builtin_amdgcn_permlane32_swap)
    auto r = __builtin_amdgcn_permlane32_swap(__float_as_uint(v), __float_as_uint(v), false, false);
    return __uint_as_float(r[0]) + __uint_as_float(r[1]);
#else
    return v + __shfl_xor(v, 32);
#endif
}

__global__ __launch_bounds__(BT, 2)   // R8 lesson: don't clamp VGPRs below need
void afm_mfma16i_kernel(const float* __restrict__ x,    // (B,40,64)
                        const float* __restrict__ W1,   // (64,64)
                        const float* __restrict__ b1,   // (64)
                        const float* __restrict__ W2,   // (1,64)
                        const float* __restrict__ Wl,   // (1,64)
                        const float* __restrict__ blp,  // (1)
                        float* __restrict__ out)        // (B,1)
{
    __shared__ __align__(16) unsigned char sxh[GPB * NF * 128];  // 20480 B
    __shared__ __align__(16) unsigned char sfrag[10 * 64 * 16];  // 10240 B
    __shared__ unsigned short srct[784];                         // r | c<<8 (padded)
    __shared__ float sred[8][2];                                 // per-wave {le, les}

    const int tid  = threadIdx.x;
    const int lane = tid & 63;
    const int w    = tid >> 6;        // wave id 0..7
    const int gb   = w >> 1;          // local batch 0..3
    const int half = w & 1;           // which half of the tile range
    const int ln15 = lane & 15;
    const int g    = lane >> 4;       // 0..3 : k-group / row-group
    const int cg   = g << 4;          // per-lane 16B slot offset

    const int b0 = blockIdx.x * GPB + gb;
    unsigned char* sxw = sxh + gb * (NF * 128);

    // ---- wave pair stages its batch's x -> fp16 LDS (5 float4 per lane) ----
    {
        const float4* xg = (const float4*)(x + (size_t)b0 * NF * ED);
        const int llp = half * 64 + lane;         // 0..127 within the pair
        #pragma unroll
        for (int i = 0; i < 5; ++i) {
            const int u = llp + i * 128;          // 640 float4 per batch
            float4 v = xg[u];
            const int r = u >> 4, j = u & 15;
            union { fp16x2 h2[2]; unsigned long long ll; } pk;
            pk.h2[0] = __builtin_amdgcn_cvt_pkrtz(v.x, v.y);
            pk.h2[1] = __builtin_amdgcn_cvt_pkrtz(v.z, v.w);
            const int byteoff = r * 128 + (((j >> 1) ^ (r & 7)) << 4) + (j & 1) * 8;
            *(unsigned long long*)(sxw + byteoff) = pk.ll;
        }
    }

    // ---- all 512 threads cooperatively build the 640 fragment slots ----
    for (int slot = tid; slot < 640; slot += BT) {
        const int f = slot >> 6, l = slot & 63;
        const int lg = l >> 4, l15 = l & 15;
        const float* src = (f < 8)
            ? (W1 + ((f >> 1) * 16 + l15) * ED + (f & 1) * 32 + lg * 8)
            : (Wl + (f - 8) * 32 + lg * 8);
        union { fp16x2 h2[4]; f16x8 h8; } u;
        u.h2[0] = __builtin_amdgcn_cvt_pkrtz(src[0], src[1]);
        u.h2[1] = __builtin_amdgcn_cvt_pkrtz(src[2], src[3]);
        u.h2[2] = __builtin_amdgcn_cvt_pkrtz(src[4], src[5]);
        u.h2[3] = __builtin_amdgcn_cvt_pkrtz(src[6], src[7]);
        *(f16x8*)(sfrag + slot * 16) = u.h8;
    }
    // ---- (r,c) table, padded to 784 ----
    for (int p = tid; p < 784; p += BT) {
        const int pq = p < NP ? p : NP - 1;
        const int r = (int)((79.0f - sqrtf(6241.0f - 8.0f * (float)pq)) * 0.5f);
        const int c = pq - ((r * (79 - r)) >> 1) + r + 1;
        srct[p] = (unsigned short)(r | (c << 8));
    }

    // ---- per-lane constants; w2 prescaled by log2(e) so exp2 replaces exp ----
    f32x4  b1v[4];
    fp16x2 w2h[4][2];
    #pragma unroll
    for (int mf = 0; mf < 4; ++mf) {
        float4 wv = *(const float4*)(W2 + mf * 16 + g * 4);
        b1v[mf] = *(const f32x4*)(b1 + mf * 16 + g * 4);
        const float L2E = 1.4426950408889634f;
        w2h[mf][0] = __builtin_amdgcn_cvt_pkrtz(wv.x * L2E, wv.y * L2E);
        w2h[mf][1] = __builtin_amdgcn_cvt_pkrtz(wv.z * L2E, wv.w * L2E);
    }
    const float blv = blp[0];

    __syncthreads();

    // ---- read shared fragments (identical per-lane across waves) ----
    f16x8 Ah[4][2], Awl[2];
    #pragma unroll
    for (int mf = 0; mf < 4; ++mf)
        #pragma unroll
        for (int ks = 0; ks < 2; ++ks)
            Ah[mf][ks] = *(const f16x8*)(sfrag + ((mf * 2 + ks) * 64 + lane) * 16);
    #pragma unroll
    for (int ks = 0; ks < 2; ++ks)
        Awl[ks] = *(const f16x8*)(sfrag + ((8 + ks) * 64 + lane) * 16);

    const f32x4 zero4 = {0.f, 0.f, 0.f, 0.f};
    const fp16x2 zh = {(__fp16)0.f, (__fp16)0.f};

    // ---- this wave's share of the 49 tiles ----
    const int t0 = half ? 25 : 0;
    const int t1 = half ? NTT : 25;

    float le = 0.f, les = 0.f;
    #pragma unroll 2
    for (int tile = t0; tile < t1; ++tile) {
        const int p = tile * 16 + ln15;            // 0..783 (table padded)
        const unsigned int rc = srct[p];
        const int r = rc & 255, c = rc >> 8;

        // B fragment: ks=1 slot is exactly (ks=0 slot)^64 under the XOR swizzle
        const int offr = (r << 7) + (cg ^ ((r & 7) << 4));
        const int offc = (c << 7) + (cg ^ ((c & 7) << 4));
        f16x8 xr0 = *(const f16x8*)(sxw + offr);
        f16x8 xr1 = *(const f16x8*)(sxw + (offr ^ 64));
        f16x8 xc0 = *(const f16x8*)(sxw + offc);
        f16x8 xc1 = *(const f16x8*)(sxw + (offc ^ 64));
        f16x8 Bf0 = xr0 * xc0;                     // 4x v_pk_mul_f16 each
        f16x8 Bf1 = xr1 * xc1;

        // s_p = inner_p . Wl on the MFMA pipe (Wl broadcast A): all lanes get s_p
        f32x4 sacc;
        sacc = __builtin_amdgcn_mfma_f32_16x16x32_f16(Awl[0], Bf0, zero4, 0, 0, 0);
        sacc = __builtin_amdgcn_mfma_f32_16x16x32_f16(Awl[1], Bf1, sacc, 0, 0, 0);

        // h^T = W1 @ inner^T + b1 (b1 seeded through the MFMA C operand)
        f32x4 acc[4];
        #pragma unroll
        for (int mf = 0; mf < 4; ++mf) {
            acc[mf] = __builtin_amdgcn_mfma_f32_16x16x32_f16(Ah[mf][0], Bf0, b1v[mf], 0, 0, 0);
            acc[mf] = __builtin_amdgcn_mfma_f32_16x16x32_f16(Ah[mf][1], Bf1, acc[mf], 0, 0, 0);
        }

        // logit*log2e = sum_m w2[m]*relu(h[m][p]) via pkrtz + pk_max + fdot2
        float q0 = 0.f, q1 = 0.f;
        #pragma unroll
        for (int mf = 0; mf < 4; ++mf) {
            fp16x2 h01 = __builtin_amdgcn_cvt_pkrtz(acc[mf][0], acc[mf][1]);
            fp16x2 h23 = __builtin_amdgcn_cvt_pkrtz(acc[mf][2], acc[mf][3]);
            h01 = __builtin_elementwise_max(h01, zh);
            h23 = __builtin_elementwise_max(h23, zh);
            if (mf & 1) {
                q1 = __builtin_amdgcn_fdot2(h01, w2h[mf][0], q1, false);
                q1 = __builtin_amdgcn_fdot2(h23, w2h[mf][1], q1, false);
            } else {
                q0 = __builtin_amdgcn_fdot2(h01, w2h[mf][0], q0, false);
                q0 = __builtin_amdgcn_fdot2(h23, w2h[mf][1], q0, false);
            }
        }
        // cross-g reduction on the VALU (permlane swaps), not the LDS pipe
        float part = xadd32(xadd16(q0 + q1));

        // fused softmax accumulation (no max-sub: logits O(1), validated R7)
        const float e_ = (p < NP) ? exp2f(part) : 0.f;
        le  += e_;
        les  = fmaf(e_, sacc[0], les);
    }

    // reduce over ln15 within 16-lane groups (g-copies identical; each pair once)
    #pragma unroll
    for (int off = 1; off < 16; off <<= 1) {
        le  += __shfl_xor(le, off);
        les += __shfl_xor(les, off);
    }
    if (lane == 0) { sred[w][0] = le; sred[w][1] = les; }
    __syncthreads();

    // combine the wave pair and write the scalar
    if (half == 0 && lane == 0) {
        const float E  = sred[w][0] + sred[w + 1][0];
        const float ES = sred[w][1] + sred[w + 1][1];
        out[b0] = ES / E + blv;
    }
}

extern "C" void kernel_launch(void* const* d_in, const int* in_sizes, int n_in,
                              void* d_out, int out_size, void* d_ws, size_t ws_size,
                              hipStream_t stream) {
    const float* x  = (const float*)d_in[0];
    const float* W1 = (const float*)d_in[1];
    const float* b1 = (const float*)d_in[2];
    const float* W2 = (const float*)d_in[3];
    // d_in[4] = b2 : cancels in softmax, unused
    const float* Wl = (const float*)d_in[5];
    const float* bl = (const float*)d_in[6];
    float* out = (float*)d_out;

    const int B = in_sizes[0] / (NF * ED);   // 2048
    afm_mfma16i_kernel<<<B / GPB, BT, 0, stream>>>(x, W1, b1, W2, Wl, bl, out);
}

// Round 13
// 26.464 us; speedup vs baseline: 1.0202x; 1.0202x over previous
//
#include <hip/hip_runtime.h>
#include <math.h>

#define NF 40
#define ED 64
#define NP 780      // 40*39/2
#define GPB 4       // batches per block (TWO waves each)
#define BT 512      // 8 waves
#define NTT 49      // 49 tiles x 16 pairs = 784 >= 780 (table padded to 50)

typedef __attribute__((ext_vector_type(8))) _Float16 f16x8;
typedef __attribute__((ext_vector_type(2))) __fp16  fp16x2;
typedef __attribute__((ext_vector_type(4))) float   f32x4;

__global__ __launch_bounds__(BT, 2)   // R8 lesson: don't clamp VGPRs below need
void afm_mfma16j_kernel(const float* __restrict__ x,    // (B,40,64)
                        const float* __restrict__ W1,   // (64,64)
                        const float* __restrict__ b1,   // (64)
                        const float* __restrict__ W2,   // (1,64)
                        const float* __restrict__ Wl,   // (1,64)
                        const float* __restrict__ blp,  // (1)
                        float* __restrict__ out)        // (B,1)
{
    __shared__ __align__(16) unsigned char sxh[GPB * NF * 128];  // 20480 B
    __shared__ __align__(16) unsigned char sfrag[10 * 64 * 16];  // 10240 B
    __shared__ unsigned int srctw[800];   // pre-swizzled {offr | offc<<16}, padded
    __shared__ float sred[8][2];          // per-wave {le, les}
    // total ~34 KB -> 2 blocks/CU (grid 512 = 2/CU)

    const int tid  = threadIdx.x;
    const int lane = tid & 63;
    const int w    = tid >> 6;        // wave id 0..7
    const int gb   = w >> 1;          // local batch 0..3
    const int half = w & 1;           // which half of the tile range
    const int ln15 = lane & 15;
    const int g    = lane >> 4;       // 0..3 : k-group / row-group
    const int cg   = g << 4;          // per-lane 16B slot offset (bits 4-5)

    const int b0 = blockIdx.x * GPB + gb;
    unsigned char* sxw = sxh + gb * (NF * 128);

    // ---- wave pair stages its batch's x -> fp16 LDS (5 float4 per lane) ----
    {
        const float4* xg = (const float4*)(x + (size_t)b0 * NF * ED);
        const int llp = half * 64 + lane;         // 0..127 within the pair
        #pragma unroll
        for (int i = 0; i < 5; ++i) {
            const int u = llp + i * 128;          // 640 float4 per batch
            float4 v = xg[u];
            const int r = u >> 4, j = u & 15;
            union { fp16x2 h2[2]; unsigned long long ll; } pk;
            pk.h2[0] = __builtin_amdgcn_cvt_pkrtz(v.x, v.y);
            pk.h2[1] = __builtin_amdgcn_cvt_pkrtz(v.z, v.w);
            const int byteoff = r * 128 + (((j >> 1) ^ (r & 7)) << 4) + (j & 1) * 8;
            *(unsigned long long*)(sxw + byteoff) = pk.ll;
        }
    }

    // ---- all 512 threads cooperatively build the 640 fragment slots ----
    for (int slot = tid; slot < 640; slot += BT) {
        const int f = slot >> 6, l = slot & 63;
        const int lg = l >> 4, l15 = l & 15;
        const float* src = (f < 8)
            ? (W1 + ((f >> 1) * 16 + l15) * ED + (f & 1) * 32 + lg * 8)
            : (Wl + (f - 8) * 32 + lg * 8);
        union { fp16x2 h2[4]; f16x8 h8; } u;
        u.h2[0] = __builtin_amdgcn_cvt_pkrtz(src[0], src[1]);
        u.h2[1] = __builtin_amdgcn_cvt_pkrtz(src[2], src[3]);
        u.h2[2] = __builtin_amdgcn_cvt_pkrtz(src[4], src[5]);
        u.h2[3] = __builtin_amdgcn_cvt_pkrtz(src[6], src[7]);
        *(f16x8*)(sfrag + slot * 16) = u.h8;
    }
    // ---- pre-swizzled (r,c) offset table, padded to 800 entries ----
    for (int p = tid; p < 800; p += BT) {
        const int pq = p < NP ? p : NP - 1;
        const int r = (int)((79.0f - sqrtf(6241.0f - 8.0f * (float)pq)) * 0.5f);
        const int c = pq - ((r * (79 - r)) >> 1) + r + 1;
        const unsigned int er = (unsigned int)((r << 7) | ((r & 7) << 4));
        const unsigned int ec = (unsigned int)((c << 7) | ((c & 7) << 4));
        srctw[p] = er | (ec << 16);
    }

    // ---- per-lane constants; w2 prescaled by log2(e) so exp2 replaces exp ----
    f32x4  b1v[4];
    fp16x2 w2h[4][2];
    #pragma unroll
    for (int mf = 0; mf < 4; ++mf) {
        float4 wv = *(const float4*)(W2 + mf * 16 + g * 4);
        b1v[mf] = *(const f32x4*)(b1 + mf * 16 + g * 4);
        const float L2E = 1.4426950408889634f;
        w2h[mf][0] = __builtin_amdgcn_cvt_pkrtz(wv.x * L2E, wv.y * L2E);
        w2h[mf][1] = __builtin_amdgcn_cvt_pkrtz(wv.z * L2E, wv.w * L2E);
    }
    const float blv = blp[0];

    __syncthreads();

    // ---- read shared fragments (identical per-lane across waves) ----
    f16x8 Ah[4][2], Awl[2];
    #pragma unroll
    for (int mf = 0; mf < 4; ++mf)
        #pragma unroll
        for (int ks = 0; ks < 2; ++ks)
            Ah[mf][ks] = *(const f16x8*)(sfrag + ((mf * 2 + ks) * 64 + lane) * 16);
    #pragma unroll
    for (int ks = 0; ks < 2; ++ks)
        Awl[ks] = *(const f16x8*)(sfrag + ((8 + ks) * 64 + lane) * 16);

    const f32x4 zero4 = {0.f, 0.f, 0.f, 0.f};
    const fp16x2 zh = {(__fp16)0.f, (__fp16)0.f};

    // ---- this wave's share of the 49 tiles ----
    const int t0 = half ? 25 : 0;
    const int t1 = half ? NTT : 25;

    // ---- software-pipelined main loop: prefetch tile t+1 while computing t ----
    unsigned int rc = srctw[t0 * 16 + ln15];
    int offr = (int)(rc & 0xffffu) ^ cg;
    int offc = (int)(rc >> 16) ^ cg;
    f16x8 xr0 = *(const f16x8*)(sxw + offr);
    f16x8 xr1 = *(const f16x8*)(sxw + (offr ^ 64));
    f16x8 xc0 = *(const f16x8*)(sxw + offc);
    f16x8 xc1 = *(const f16x8*)(sxw + (offc ^ 64));

    float le = 0.f, les = 0.f;
    for (int tile = t0; tile < t1; ++tile) {
        // ---- issue next tile's loads (table padded -> unconditional) ----
        const unsigned int rcn = srctw[(tile + 1) * 16 + ln15];
        const int offrn = (int)(rcn & 0xffffu) ^ cg;
        const int offcn = (int)(rcn >> 16) ^ cg;
        f16x8 nr0 = *(const f16x8*)(sxw + offrn);
        f16x8 nr1 = *(const f16x8*)(sxw + (offrn ^ 64));
        f16x8 nc0 = *(const f16x8*)(sxw + offcn);
        f16x8 nc1 = *(const f16x8*)(sxw + (offcn ^ 64));

        // ---- compute current tile ----
        f16x8 Bf0 = xr0 * xc0;                     // 4x v_pk_mul_f16 each
        f16x8 Bf1 = xr1 * xc1;

        // s_p = inner_p . Wl on the MFMA pipe (Wl broadcast A)
        f32x4 sacc;
        sacc = __builtin_amdgcn_mfma_f32_16x16x32_f16(Awl[0], Bf0, zero4, 0, 0, 0);
        sacc = __builtin_amdgcn_mfma_f32_16x16x32_f16(Awl[1], Bf1, sacc, 0, 0, 0);

        // h^T = W1 @ inner^T + b1 (b1 seeded through the MFMA C operand)
        f32x4 acc[4];
        #pragma unroll
        for (int mf = 0; mf < 4; ++mf) {
            acc[mf] = __builtin_amdgcn_mfma_f32_16x16x32_f16(Ah[mf][0], Bf0, b1v[mf], 0, 0, 0);
            acc[mf] = __builtin_amdgcn_mfma_f32_16x16x32_f16(Ah[mf][1], Bf1, acc[mf], 0, 0, 0);
        }

        // logit*log2e = sum_m w2[m]*relu(h[m][p]) via pkrtz + pk_max + fdot2
        float q0 = 0.f, q1 = 0.f;
        #pragma unroll
        for (int mf = 0; mf < 4; ++mf) {
            fp16x2 h01 = __builtin_amdgcn_cvt_pkrtz(acc[mf][0], acc[mf][1]);
            fp16x2 h23 = __builtin_amdgcn_cvt_pkrtz(acc[mf][2], acc[mf][3]);
            h01 = __builtin_elementwise_max(h01, zh);
            h23 = __builtin_elementwise_max(h23, zh);
            if (mf & 1) {
                q1 = __builtin_amdgcn_fdot2(h01, w2h[mf][0], q1, false);
                q1 = __builtin_amdgcn_fdot2(h23, w2h[mf][1], q1, false);
            } else {
                q0 = __builtin_amdgcn_fdot2(h01, w2h[mf][0], q0, false);
                q0 = __builtin_amdgcn_fdot2(h23, w2h[mf][1], q0, false);
            }
        }
        float part = q0 + q1;
        part += __shfl_xor(part, 16);      // cross-g on the LDS pipe (R12 lesson)
        part += __shfl_xor(part, 32);

        // fused softmax accumulation (no max-sub: logits O(1), validated R7)
        const int p = tile * 16 + ln15;
        const float e_ = (p < NP) ? exp2f(part) : 0.f;
        le  += e_;
        les  = fmaf(e_, sacc[0], les);

        // rotate pipeline registers
        xr0 = nr0; xr1 = nr1; xc0 = nc0; xc1 = nc1;
    }

    // reduce over ln15 within 16-lane groups (g-copies identical; each pair once)
    #pragma unroll
    for (int off = 1; off < 16; off <<= 1) {
        le  += __shfl_xor(le, off);
        les += __shfl_xor(les, off);
    }
    if (lane == 0) { sred[w][0] = le; sred[w][1] = les; }
    __syncthreads();

    // combine the wave pair and write the scalar
    if (half == 0 && lane == 0) {
        const float E  = sred[w][0] + sred[w + 1][0];
        const float ES = sred[w][1] + sred[w + 1][1];
        out[b0] = ES / E + blv;
    }
}

extern "C" void kernel_launch(void* const* d_in, const int* in_sizes, int n_in,
                              void* d_out, int out_size, void* d_ws, size_t ws_size,
                              hipStream_t stream) {
    const float* x  = (const float*)d_in[0];
    const float* W1 = (const float*)d_in[1];
    const float* b1 = (const float*)d_in[2];
    const float* W2 = (const float*)d_in[3];
    // d_in[4] = b2 : cancels in softmax, unused
    const float* Wl = (const float*)d_in[5];
    const float* bl = (const float*)d_in[6];
    float* out = (float*)d_out;

    const int B = in_sizes[0] / (NF * ED);   // 2048
    afm_mfma16j_kernel<<<B / GPB, BT, 0, stream>>>(x, W1, b1, W2, Wl, bl, out);
}